// Round 6
// baseline (308.063 us; speedup 1.0000x reference)
//
#include <hip/hip_runtime.h>
#include <hip/hip_bf16.h>

#define DIM   512
#define QKVD  1536
#define HEADS 8
#define HD    64
#define NSEQ  4096
#define LDP   72    // padded stride for transpose staging (144B, conflict-free)
#define LDPK  72
#define LDPV  136   // 272B stride, conflict-free b128
#define SCALE_LOG2E 0.18033688011112042f   // 0.125 * log2(e), folded into Q

typedef float  f32x4  __attribute__((ext_vector_type(4)));
typedef __bf16 bf16x8 __attribute__((ext_vector_type(8)));
typedef __bf16 bf16x4 __attribute__((ext_vector_type(4)));
typedef short  s16x4  __attribute__((ext_vector_type(4)));

static __device__ inline f32x4 mfma32(bf16x8 a, bf16x8 b, f32x4 c) {
  return __builtin_amdgcn_mfma_f32_16x16x32_bf16(a, b, c, 0, 0, 0);
}
static __device__ inline s16x4 pack_bf16(f32x4 v) {
  bf16x4 b = __builtin_convertvector(v, bf16x4);
  return __builtin_bit_cast(s16x4, b);
}
// async global->LDS DMA, 16B per lane; LDS dest = wave-uniform base + lane*16.
static __device__ inline void gl_lds16(const __bf16* g, __bf16* l) {
  __builtin_amdgcn_global_load_lds(
      (const __attribute__((address_space(1))) unsigned int*)g,
      (__attribute__((address_space(3))) unsigned int*)l, 16, 0, 0);
}

// One fused conversion pass: x (1048576 vec4) + qkv_w (196608) + proj_w (65536)
// = 1310720 vec4 = 5120 blocks x 256 threads exactly.
__global__ __launch_bounds__(256) void cvt_all(const float* __restrict__ x,
                                               const float* __restrict__ qkv_w,
                                               const float* __restrict__ proj_w,
                                               __bf16* __restrict__ xb,
                                               __bf16* __restrict__ wqkv,
                                               __bf16* __restrict__ wproj) {
  int i = blockIdx.x * 256 + threadIdx.x;
  const float* s; __bf16* d; int off;
  if (i < 1048576)                 { s = x;      d = xb;    off = i; }
  else if (i < 1048576 + 196608)   { s = qkv_w;  d = wqkv;  off = i - 1048576; }
  else                             { s = proj_w; d = wproj; off = i - 1245184; }
  f32x4 v = ((const f32x4*)s)[off];
  *(bf16x4*)(d + 4 * (size_t)off) = __builtin_convertvector(v, bf16x4);
}

// 128x128-tile GEMM, global_load_lds staging (linear [row][64] LDS):
// nt 0..7:  C[m][oc] = A * Bw^T + bias  (Q cols scaled by 0.125*log2e)
// nt 8..11: V columns are NOT written to C; instead transposed in-block
//           (transpose_v's exact padded-stride-72 pattern + key permutation)
//           and stored directly to Vt[bh][d][perm(n)].
__global__ __launch_bounds__(256) void gemm_qkv(const __bf16* __restrict__ A,
                                                const __bf16* __restrict__ Bw,
                                                const float* __restrict__ bias,
                                                __bf16* __restrict__ C,
                                                __bf16* __restrict__ Vt) {
  const int mt = blockIdx.x;   // 0..63
  const int nt = blockIdx.y;   // 0..11
  __shared__ __bf16 S[2 * 128 * 64];   // 32 KB: As | Bs; reused as T[128][72]
  __bf16* As = S;
  __bf16* Bs = S + 128 * 64;
  const int tid = threadIdx.x, w = tid >> 6, lane = tid & 63;
  const int l16 = lane & 15, quad = lane >> 4;
  // staging geometry: chunk = 8 rows x 64 cols = 1024 B = one wave-issue.
  const int ch0 = w << 2;
  const int lrow = lane >> 3, lcol = (lane & 7) << 3;

  f32x4 acc[2][8] = {};
  for (int kt = 0; kt < 8; ++kt) {
    __syncthreads();   // previous compute done; safe to overwrite LDS
    const __bf16* Ak = A + (size_t)(mt * 128) * DIM + kt * 64;
    const __bf16* Bk = Bw + (size_t)(nt * 128) * DIM + kt * 64;
#pragma unroll
    for (int i = 0; i < 4; ++i) {
      int ch = ch0 + i;
      gl_lds16(Ak + (size_t)(ch * 8 + lrow) * DIM + lcol, As + ch * 512);
      gl_lds16(Bk + (size_t)(ch * 8 + lrow) * DIM + lcol, Bs + ch * 512);
    }
    __syncthreads();   // vmcnt(0) drained before barrier -> tile ready
#pragma unroll
    for (int c = 0; c < 2; ++c) {
      bf16x8 a[2];
#pragma unroll
      for (int mtt = 0; mtt < 2; ++mtt)
        a[mtt] = *(const bf16x8*)(As + (w * 32 + mtt * 16 + l16) * 64 + quad * 8 + c * 32);
#pragma unroll
      for (int ct = 0; ct < 8; ++ct) {
        bf16x8 bb = *(const bf16x8*)(Bs + (ct * 16 + l16) * 64 + quad * 8 + c * 32);
#pragma unroll
        for (int mtt = 0; mtt < 2; ++mtt)
          acc[mtt][ct] = mfma32(a[mtt], bb, acc[mtt][ct]);
      }
    }
  }

  if (nt < 8) {
    const float sc = (nt < 4) ? SCALE_LOG2E : 1.0f;   // nt 0..3 = Q columns
#pragma unroll
    for (int ct = 0; ct < 8; ++ct) {
      int oc = nt * 128 + ct * 16 + l16;
      float bv = bias[oc];
#pragma unroll
      for (int mtt = 0; mtt < 2; ++mtt)
#pragma unroll
        for (int r = 0; r < 4; ++r) {
          int mrow = mt * 128 + w * 32 + mtt * 16 + quad * 4 + r;
          C[(size_t)mrow * QKVD + oc] = (__bf16)((acc[mtt][ct][r] + bv) * sc);
        }
    }
  } else {
    // V tile: 128 tokens x 128 dims = heads 2*(nt-8), 2*(nt-8)+1.
    // Two passes (one head / 64 cols each) through T[128][LDP] in LDS.
    __bf16* T = S;   // 128*72*2 = 18432 B <= 32768 B
#pragma unroll 1
    for (int pass = 0; pass < 2; ++pass) {
      __syncthreads();   // staging reads (or prev pass reads) done
#pragma unroll
      for (int ct4 = 0; ct4 < 4; ++ct4) {
        int ct = pass * 4 + ct4;
        int oc = nt * 128 + ct * 16 + l16;
        float bv = bias[oc];
        int col = ct4 * 16 + l16;   // 0..63 within head
#pragma unroll
        for (int mtt = 0; mtt < 2; ++mtt)
#pragma unroll
          for (int r = 0; r < 4; ++r) {
            int rowl = w * 32 + mtt * 16 + quad * 4 + r;   // 0..127
            T[rowl * LDP + col] = (__bf16)(acc[mtt][ct][r] + bv);
          }
      }
      __syncthreads();
      // transposed store with transpose_v's exact key permutation
      const int h = (nt - 8) * 2 + pass;
      const int d = tid >> 2, t = tid & 3;
      const int g2 = t >> 1, m2 = t & 1;
#pragma unroll
      for (int sub = 0; sub < 2; ++sub) {
        int mrow0 = mt * 128 + sub * 64;        // global token base of sub-block
        int b = mrow0 >> 12;                    // batch
        int n64 = (mrow0 & 4095) >> 6;          // 64-key block within batch
        __bf16* dst = Vt + ((size_t)(b * 8 + h) * HD + d) * NSEQ +
                      n64 * 64 + g2 * 32 + m2 * 4;
#pragma unroll
        for (int u = 0; u < 4; ++u) {
          bf16x4 o;
#pragma unroll
          for (int jj = 0; jj < 4; ++jj)
            o[jj] = T[(sub * 64 + t * 16 + u * 4 + jj) * LDP + d];
          *(bf16x4*)(dst + u * 8) = o;
        }
      }
    }
  }
}

// 128x64-tile GEMM, global_load_lds staging, fp32 output:
// out = A[8192x512] * Bw[512x512]^T + bias.
__global__ __launch_bounds__(256) void gemm_proj(const __bf16* __restrict__ A,
                                                 const __bf16* __restrict__ Bw,
                                                 const float* __restrict__ bias,
                                                 float* __restrict__ C) {
  const int mt = blockIdx.x;   // 0..63
  const int nt = blockIdx.y;   // 0..7
  __shared__ __bf16 As[128 * 64];   // 16 KB linear
  __shared__ __bf16 Bs[64 * 64];    // 8 KB linear
  const int tid = threadIdx.x, w = tid >> 6, lane = tid & 63;
  const int l16 = lane & 15, quad = lane >> 4;
  const int lrow = lane >> 3, lcol = (lane & 7) << 3;
  const int cha0 = w << 2;   // 4 A-chunks per wave (16 total)
  const int chb0 = w << 1;   // 2 B-chunks per wave (8 total)

  f32x4 acc[2][4] = {};
  for (int kt = 0; kt < 8; ++kt) {
    __syncthreads();
    const __bf16* Ak = A + (size_t)(mt * 128) * DIM + kt * 64;
    const __bf16* Bk = Bw + (size_t)(nt * 64) * DIM + kt * 64;
#pragma unroll
    for (int i = 0; i < 4; ++i) {
      int ch = cha0 + i;
      gl_lds16(Ak + (size_t)(ch * 8 + lrow) * DIM + lcol, As + ch * 512);
    }
#pragma unroll
    for (int i = 0; i < 2; ++i) {
      int ch = chb0 + i;
      gl_lds16(Bk + (size_t)(ch * 8 + lrow) * DIM + lcol, Bs + ch * 512);
    }
    __syncthreads();
#pragma unroll
    for (int c = 0; c < 2; ++c) {
      bf16x8 a[2];
#pragma unroll
      for (int mtt = 0; mtt < 2; ++mtt)
        a[mtt] = *(const bf16x8*)(As + (w * 32 + mtt * 16 + l16) * 64 + quad * 8 + c * 32);
#pragma unroll
      for (int ct = 0; ct < 4; ++ct) {
        bf16x8 bb = *(const bf16x8*)(Bs + (ct * 16 + l16) * 64 + quad * 8 + c * 32);
#pragma unroll
        for (int mtt = 0; mtt < 2; ++mtt)
          acc[mtt][ct] = mfma32(a[mtt], bb, acc[mtt][ct]);
      }
    }
  }
#pragma unroll
  for (int ct = 0; ct < 4; ++ct) {
    int oc = nt * 64 + ct * 16 + l16;
    float bv = bias[oc];
#pragma unroll
    for (int mtt = 0; mtt < 2; ++mtt)
#pragma unroll
      for (int r = 0; r < 4; ++r) {
        int mrow = mt * 128 + w * 32 + mtt * 16 + quad * 4 + r;
        C[(size_t)mrow * DIM + oc] = acc[mtt][ct][r] + bv;
      }
  }
}

// Flash attention v7 (round-0 best, 72.6us) verbatim: 512-thread block = two
// 4-wave groups; group g handles keys g*2048..g*2048+2047 over the block's
// 256 q rows (wave wg owns 64 rows, mt=4). Max-free softmax -> partials
// combine by addition: group 1's unnormalized O + l (MFMA ones-column)
// exchanged via LDS, group 0 normalizes.
// NOTE (r4): s_setprio around the g-loop measured -20% here (lockstep
// barrier-synced structure, m190 case) -- do not re-add.
__global__ __launch_bounds__(512, 2) void attn_fused(const __bf16* __restrict__ QKV,
                                                     const __bf16* __restrict__ Vtp,
                                                     __bf16* __restrict__ Og) {
  const int qt = blockIdx.x;   // 0..15 (256 q rows)
  const int bh = blockIdx.y;   // 0..15
  const int b = bh >> 3, h = bh & 7;

  __shared__ __align__(16) char smem[81920];
  __bf16* KsAll  = (__bf16*)smem;               // [2][128*LDPK] = 36864 B
  __bf16* VtsAll = (__bf16*)(smem + 36864);     // [2][64*LDPV]  = 34816 B
  float*  Oex    = (float*)smem;                // 81920 B (after compute)

  const int tid = threadIdx.x, w = tid >> 6, lane = tid & 63;
  const int wg = w & 3, grp = w >> 2;
  const int l16 = lane & 15, quad = lane >> 4;
  const int g256 = tid & 255;

  __bf16* Ks  = KsAll + grp * (128 * LDPK);
  __bf16* Vts = VtsAll + grp * (64 * LDPV);

  const __bf16* Qb = QKV + (size_t)(b * NSEQ + qt * 256) * QKVD + h * 64;
  const __bf16* Kb = QKV + ((size_t)b * NSEQ + (size_t)grp * 2048) * QKVD + 512 + h * 64;
  const __bf16* Vp = Vtp + (size_t)bh * HD * NSEQ + grp * 2048;

  // Q fragments (one-time); both groups load the same rows
  bf16x8 aq[4][2];
#pragma unroll
  for (int mt = 0; mt < 4; ++mt)
#pragma unroll
    for (int c = 0; c < 2; ++c)
      aq[mt][c] = *(const bf16x8*)(Qb + (size_t)(wg * 64 + mt * 16 + l16) * QKVD +
                                   quad * 8 + c * 32);

  int krow[4], kc8[4], vd[4], vp8[4];
#pragma unroll
  for (int i = 0; i < 4; ++i) {
    int ch = g256 + i * 256;
    krow[i] = ch >> 3; kc8[i] = (ch & 7) << 3;
    vd[i] = ch >> 4;   vp8[i] = (ch & 15) << 3;
  }

  bf16x8 kreg[4], vreg[4];
#pragma unroll
  for (int i = 0; i < 4; ++i) {
    kreg[i] = *(const bf16x8*)(Kb + (size_t)krow[i] * QKVD + kc8[i]);
    vreg[i] = *(const bf16x8*)(Vp + (size_t)vd[i] * NSEQ + vp8[i]);
  }

  bf16x8 ones;
#pragma unroll
  for (int j = 0; j < 8; ++j) ones[j] = (__bf16)1.0f;

  f32x4 Oacc[4][5] = {};   // dt 0..3 = O, dt 4 = l (ones-column)

  for (int kt = 0; kt < 16; ++kt) {
    __syncthreads();
#pragma unroll
    for (int i = 0; i < 4; ++i) {
      *(bf16x8*)(Ks + krow[i] * LDPK + kc8[i]) = kreg[i];
      *(bf16x8*)(Vts + vd[i] * LDPV + vp8[i]) = vreg[i];
    }
    __syncthreads();

    if (kt + 1 < 16) {
      const __bf16* Kn = Kb + (size_t)(kt + 1) * 128 * QKVD;
      const __bf16* Vn = Vp + (size_t)(kt + 1) * 128;
#pragma unroll
      for (int i = 0; i < 4; ++i) {
        kreg[i] = *(const bf16x8*)(Kn + (size_t)krow[i] * QKVD + kc8[i]);
        vreg[i] = *(const bf16x8*)(Vn + (size_t)vd[i] * NSEQ + vp8[i]);
      }
    }

#pragma unroll
    for (int g = 0; g < 4; ++g) {
      bf16x8 kb[2][2];
#pragma unroll
      for (int e = 0; e < 2; ++e)
#pragma unroll
        for (int c = 0; c < 2; ++c)
          kb[e][c] = *(const bf16x8*)(Ks + ((2 * g + e) * 16 + l16) * LDPK +
                                      quad * 8 + c * 32);
      bf16x8 ap[4];
#pragma unroll
      for (int mt = 0; mt < 4; ++mt) {
        f32x4 a0 = {}, a1 = {};
        a0 = mfma32(kb[0][0], aq[mt][0], a0);
        a0 = mfma32(kb[0][1], aq[mt][1], a0);
        a1 = mfma32(kb[1][0], aq[mt][0], a1);
        a1 = mfma32(kb[1][1], aq[mt][1], a1);
        f32x4 e0, e1;
#pragma unroll
        for (int r = 0; r < 4; ++r) {
          e0[r] = __builtin_amdgcn_exp2f(a0[r]);
          e1[r] = __builtin_amdgcn_exp2f(a1[r]);
        }
        ap[mt] = __builtin_bit_cast(bf16x8,
            __builtin_shufflevector(pack_bf16(e0), pack_bf16(e1), 0, 1, 2, 3, 4, 5, 6, 7));
      }
#pragma unroll
      for (int dt = 0; dt < 4; ++dt) {
        bf16x8 bv = *(const bf16x8*)(Vts + (dt * 16 + l16) * LDPV + g * 32 + quad * 8);
#pragma unroll
        for (int mt = 0; mt < 4; ++mt)
          Oacc[mt][dt] = mfma32(ap[mt], bv, Oacc[mt][dt]);
      }
#pragma unroll
      for (int mt = 0; mt < 4; ++mt)
        Oacc[mt][4] = mfma32(ap[mt], ones, Oacc[mt][4]);   // l column
    }
  }

  // combine group partials via LDS (staging buffers are dead now)
  __syncthreads();
  if (grp == 1) {
#pragma unroll
    for (int mt = 0; mt < 4; ++mt)
#pragma unroll
      for (int dt = 0; dt < 5; ++dt)
        *(f32x4*)(Oex + (((wg * 4 + mt) * 5 + dt) << 8) + (lane << 2)) = Oacc[mt][dt];
  }
  __syncthreads();
  if (grp == 0) {
#pragma unroll
    for (int mt = 0; mt < 4; ++mt) {
#pragma unroll
      for (int dt = 0; dt < 5; ++dt)
        Oacc[mt][dt] += *(const f32x4*)(Oex + (((wg * 4 + mt) * 5 + dt) << 8) + (lane << 2));
#pragma unroll
      for (int r = 0; r < 4; ++r) {
        float inv = 1.0f / Oacc[mt][4][r];   // l for q-row quad*4+r
        int n = qt * 256 + wg * 64 + mt * 16 + quad * 4 + r;
        size_t base = ((size_t)b * NSEQ + n) * DIM + (size_t)h * HD;
#pragma unroll
        for (int dt = 0; dt < 4; ++dt)
          Og[base + dt * 16 + l16] = (__bf16)(Oacc[mt][dt][r] * inv);
      }
    }
  }
}

extern "C" void kernel_launch(void* const* d_in, const int* in_sizes, int n_in,
                              void* d_out, int out_size, void* d_ws, size_t ws_size,
                              hipStream_t stream) {
  const float* x      = (const float*)d_in[0];   // [2,4096,512]
  const float* qkv_w  = (const float*)d_in[1];   // [1536,512]
  const float* qkv_b  = (const float*)d_in[2];   // [1536]
  const float* proj_w = (const float*)d_in[3];   // [512,512]
  const float* proj_b = (const float*)d_in[4];   // [512]
  float* out = (float*)d_out;                    // [2,4096,512] fp32

  char* ws = (char*)d_ws;
  __bf16* Vtw   = (__bf16*)(ws);                 // 8 MB [B,H,HD,N] permuted
  __bf16* qkvC  = (__bf16*)(ws + 8388608);       // 24 MB [8192][1536] (V third unused)
  __bf16* wqkv  = (__bf16*)(ws + 33554432);      // 1.5 MB
  __bf16* wproj = (__bf16*)(ws + 35127296);      // 0.5 MB
  __bf16* Ob    = (__bf16*)(ws + 35651584);      // 8 MB context [m][512]
  // xb aliases Ob: xb is dead after gemm_qkv; Ob first written by attn_fused
  // (stream-ordered after gemm_qkv) -> no overlap in lifetime.
  __bf16* xb    = (__bf16*)(ws + 35651584);      // 8 MB x in bf16 [8192][512]
  // total 44,040,192 B

  cvt_all<<<5120, 256, 0, stream>>>(x, qkv_w, proj_w, xb, wqkv, wproj);
  gemm_qkv<<<dim3(64, 12), 256, 0, stream>>>(xb, wqkv, qkv_b, qkvC, Vtw);
  attn_fused<<<dim3(16, 16), 512, 0, stream>>>(qkvC, Vtw, Ob);
  gemm_proj<<<dim3(64, 8), 256, 0, stream>>>(Ob, wproj, proj_b, out);
}

// Round 7
// 183.147 us; speedup vs baseline: 1.6821x; 1.6821x over previous
//
#include <hip/hip_runtime.h>
#include <hip/hip_bf16.h>

#define DIM   512
#define QKVD  1536
#define HEADS 8
#define HD    64
#define NSEQ  4096
#define LDP   72    // padded stride for transpose staging (144B, conflict-free)
#define LDPK  72
#define LDPV  136   // 272B stride, conflict-free b128
#define SCALE_LOG2E 0.18033688011112042f   // 0.125 * log2(e), folded into Q

typedef float  f32x4  __attribute__((ext_vector_type(4)));
typedef __bf16 bf16x8 __attribute__((ext_vector_type(8)));
typedef __bf16 bf16x4 __attribute__((ext_vector_type(4)));
typedef short  s16x4  __attribute__((ext_vector_type(4)));

static __device__ inline f32x4 mfma32(bf16x8 a, bf16x8 b, f32x4 c) {
  return __builtin_amdgcn_mfma_f32_16x16x32_bf16(a, b, c, 0, 0, 0);
}
static __device__ inline s16x4 pack_bf16(f32x4 v) {
  bf16x4 b = __builtin_convertvector(v, bf16x4);
  return __builtin_bit_cast(s16x4, b);
}
// async global->LDS DMA, 16B per lane; LDS dest = wave-uniform base + lane*16.
static __device__ inline void gl_lds16(const __bf16* g, __bf16* l) {
  __builtin_amdgcn_global_load_lds(
      (const __attribute__((address_space(1))) unsigned int*)g,
      (__attribute__((address_space(3))) unsigned int*)l, 16, 0, 0);
}

// One fused conversion pass: x (1048576 vec4) + qkv_w (196608) + proj_w (65536)
// = 1310720 vec4 = 5120 blocks x 256 threads exactly.
__global__ __launch_bounds__(256) void cvt_all(const float* __restrict__ x,
                                               const float* __restrict__ qkv_w,
                                               const float* __restrict__ proj_w,
                                               __bf16* __restrict__ xb,
                                               __bf16* __restrict__ wqkv,
                                               __bf16* __restrict__ wproj) {
  int i = blockIdx.x * 256 + threadIdx.x;
  const float* s; __bf16* d; int off;
  if (i < 1048576)                 { s = x;      d = xb;    off = i; }
  else if (i < 1048576 + 196608)   { s = qkv_w;  d = wqkv;  off = i - 1048576; }
  else                             { s = proj_w; d = wproj; off = i - 1245184; }
  f32x4 v = ((const f32x4*)s)[off];
  *(bf16x4*)(d + 4 * (size_t)off) = __builtin_convertvector(v, bf16x4);
}

// 128x128-tile GEMM, global_load_lds staging (linear [row][64] LDS):
// nt 0..7:  C[m][oc] = A * Bw^T + bias  (Q cols scaled by 0.125*log2e)
// nt 8..11: V columns transposed in-block (transpose_v's exact pattern +
//           key permutation) and stored directly to Vt[bh][d][perm(n)].
// NOTE (r6): the pass loop MUST be fully unrolled -- a runtime `pass` index
// into acc[][] sends the whole accumulator to scratch (rule #20; measured
// 546 MB scratch traffic, MfmaUtil 3%).
__global__ __launch_bounds__(256) void gemm_qkv(const __bf16* __restrict__ A,
                                                const __bf16* __restrict__ Bw,
                                                const float* __restrict__ bias,
                                                __bf16* __restrict__ C,
                                                __bf16* __restrict__ Vt) {
  const int mt = blockIdx.x;   // 0..63
  const int nt = blockIdx.y;   // 0..11
  __shared__ __bf16 S[2 * 128 * 64];   // 32 KB: As | Bs; reused as T[128][72]
  __bf16* As = S;
  __bf16* Bs = S + 128 * 64;
  const int tid = threadIdx.x, w = tid >> 6, lane = tid & 63;
  const int l16 = lane & 15, quad = lane >> 4;
  // staging geometry: chunk = 8 rows x 64 cols = 1024 B = one wave-issue.
  const int ch0 = w << 2;
  const int lrow = lane >> 3, lcol = (lane & 7) << 3;

  f32x4 acc[2][8] = {};
  for (int kt = 0; kt < 8; ++kt) {
    __syncthreads();   // previous compute done; safe to overwrite LDS
    const __bf16* Ak = A + (size_t)(mt * 128) * DIM + kt * 64;
    const __bf16* Bk = Bw + (size_t)(nt * 128) * DIM + kt * 64;
#pragma unroll
    for (int i = 0; i < 4; ++i) {
      int ch = ch0 + i;
      gl_lds16(Ak + (size_t)(ch * 8 + lrow) * DIM + lcol, As + ch * 512);
      gl_lds16(Bk + (size_t)(ch * 8 + lrow) * DIM + lcol, Bs + ch * 512);
    }
    __syncthreads();   // vmcnt(0) drained before barrier -> tile ready
#pragma unroll
    for (int c = 0; c < 2; ++c) {
      bf16x8 a[2];
#pragma unroll
      for (int mtt = 0; mtt < 2; ++mtt)
        a[mtt] = *(const bf16x8*)(As + (w * 32 + mtt * 16 + l16) * 64 + quad * 8 + c * 32);
#pragma unroll
      for (int ct = 0; ct < 8; ++ct) {
        bf16x8 bb = *(const bf16x8*)(Bs + (ct * 16 + l16) * 64 + quad * 8 + c * 32);
#pragma unroll
        for (int mtt = 0; mtt < 2; ++mtt)
          acc[mtt][ct] = mfma32(a[mtt], bb, acc[mtt][ct]);
      }
    }
  }

  if (nt < 8) {
    const float sc = (nt < 4) ? SCALE_LOG2E : 1.0f;   // nt 0..3 = Q columns
#pragma unroll
    for (int ct = 0; ct < 8; ++ct) {
      int oc = nt * 128 + ct * 16 + l16;
      float bv = bias[oc];
#pragma unroll
      for (int mtt = 0; mtt < 2; ++mtt)
#pragma unroll
        for (int r = 0; r < 4; ++r) {
          int mrow = mt * 128 + w * 32 + mtt * 16 + quad * 4 + r;
          C[(size_t)mrow * QKVD + oc] = (__bf16)((acc[mtt][ct][r] + bv) * sc);
        }
    }
  } else {
    // V tile: 128 tokens x 128 dims = heads 2*(nt-8), 2*(nt-8)+1.
    // Two passes (one head / 64 cols each) through T[128][LDP] in LDS.
    __bf16* T = S;   // 128*72*2 = 18432 B <= 32768 B
#pragma unroll
    for (int pass = 0; pass < 2; ++pass) {   // FULLY unrolled: acc idx static
      __syncthreads();   // staging reads (or prev pass reads) done
#pragma unroll
      for (int ct4 = 0; ct4 < 4; ++ct4) {
        int ct = pass * 4 + ct4;
        int oc = nt * 128 + ct * 16 + l16;
        float bv = bias[oc];
        int col = ct4 * 16 + l16;   // 0..63 within head
#pragma unroll
        for (int mtt = 0; mtt < 2; ++mtt)
#pragma unroll
          for (int r = 0; r < 4; ++r) {
            int rowl = w * 32 + mtt * 16 + quad * 4 + r;   // 0..127
            T[rowl * LDP + col] = (__bf16)(acc[mtt][ct][r] + bv);
          }
      }
      __syncthreads();
      // transposed store with transpose_v's exact key permutation
      const int h = (nt - 8) * 2 + pass;
      const int d = tid >> 2, t = tid & 3;
      const int g2 = t >> 1, m2 = t & 1;
#pragma unroll
      for (int sub = 0; sub < 2; ++sub) {
        int mrow0 = mt * 128 + sub * 64;        // global token base of sub-block
        int b = mrow0 >> 12;                    // batch
        int n64 = (mrow0 & 4095) >> 6;          // 64-key block within batch
        __bf16* dst = Vt + ((size_t)(b * 8 + h) * HD + d) * NSEQ +
                      n64 * 64 + g2 * 32 + m2 * 4;
#pragma unroll
        for (int u = 0; u < 4; ++u) {
          bf16x4 o;
#pragma unroll
          for (int jj = 0; jj < 4; ++jj)
            o[jj] = T[(sub * 64 + t * 16 + u * 4 + jj) * LDP + d];
          *(bf16x4*)(dst + u * 8) = o;
        }
      }
    }
  }
}

// 128x64-tile GEMM, global_load_lds staging, fp32 output:
// out = A[8192x512] * Bw[512x512]^T + bias.
__global__ __launch_bounds__(256) void gemm_proj(const __bf16* __restrict__ A,
                                                 const __bf16* __restrict__ Bw,
                                                 const float* __restrict__ bias,
                                                 float* __restrict__ C) {
  const int mt = blockIdx.x;   // 0..63
  const int nt = blockIdx.y;   // 0..7
  __shared__ __bf16 As[128 * 64];   // 16 KB linear
  __shared__ __bf16 Bs[64 * 64];    // 8 KB linear
  const int tid = threadIdx.x, w = tid >> 6, lane = tid & 63;
  const int l16 = lane & 15, quad = lane >> 4;
  const int lrow = lane >> 3, lcol = (lane & 7) << 3;
  const int cha0 = w << 2;   // 4 A-chunks per wave (16 total)
  const int chb0 = w << 1;   // 2 B-chunks per wave (8 total)

  f32x4 acc[2][4] = {};
  for (int kt = 0; kt < 8; ++kt) {
    __syncthreads();
    const __bf16* Ak = A + (size_t)(mt * 128) * DIM + kt * 64;
    const __bf16* Bk = Bw + (size_t)(nt * 64) * DIM + kt * 64;
#pragma unroll
    for (int i = 0; i < 4; ++i) {
      int ch = cha0 + i;
      gl_lds16(Ak + (size_t)(ch * 8 + lrow) * DIM + lcol, As + ch * 512);
    }
#pragma unroll
    for (int i = 0; i < 2; ++i) {
      int ch = chb0 + i;
      gl_lds16(Bk + (size_t)(ch * 8 + lrow) * DIM + lcol, Bs + ch * 512);
    }
    __syncthreads();
#pragma unroll
    for (int c = 0; c < 2; ++c) {
      bf16x8 a[2];
#pragma unroll
      for (int mtt = 0; mtt < 2; ++mtt)
        a[mtt] = *(const bf16x8*)(As + (w * 32 + mtt * 16 + l16) * 64 + quad * 8 + c * 32);
#pragma unroll
      for (int ct = 0; ct < 4; ++ct) {
        bf16x8 bb = *(const bf16x8*)(Bs + (ct * 16 + l16) * 64 + quad * 8 + c * 32);
#pragma unroll
        for (int mtt = 0; mtt < 2; ++mtt)
          acc[mtt][ct] = mfma32(a[mtt], bb, acc[mtt][ct]);
      }
    }
  }
#pragma unroll
  for (int ct = 0; ct < 4; ++ct) {
    int oc = nt * 64 + ct * 16 + l16;
    float bv = bias[oc];
#pragma unroll
    for (int mtt = 0; mtt < 2; ++mtt)
#pragma unroll
      for (int r = 0; r < 4; ++r) {
        int mrow = mt * 128 + w * 32 + mtt * 16 + quad * 4 + r;
        C[(size_t)mrow * DIM + oc] = acc[mtt][ct][r] + bv;
      }
  }
}

// Flash attention v7 (round-0 best, 72.6us) verbatim: 512-thread block = two
// 4-wave groups; group g handles keys g*2048..g*2048+2047 over the block's
// 256 q rows (wave wg owns 64 rows, mt=4). Max-free softmax -> partials
// combine by addition: group 1's unnormalized O + l (MFMA ones-column)
// exchanged via LDS, group 0 normalizes.
// NOTE (r4): s_setprio around the g-loop measured -20% here (lockstep
// barrier-synced structure, m190 case) -- do not re-add.
__global__ __launch_bounds__(512, 2) void attn_fused(const __bf16* __restrict__ QKV,
                                                     const __bf16* __restrict__ Vtp,
                                                     __bf16* __restrict__ Og) {
  const int qt = blockIdx.x;   // 0..15 (256 q rows)
  const int bh = blockIdx.y;   // 0..15
  const int b = bh >> 3, h = bh & 7;

  __shared__ __align__(16) char smem[81920];
  __bf16* KsAll  = (__bf16*)smem;               // [2][128*LDPK] = 36864 B
  __bf16* VtsAll = (__bf16*)(smem + 36864);     // [2][64*LDPV]  = 34816 B
  float*  Oex    = (float*)smem;                // 81920 B (after compute)

  const int tid = threadIdx.x, w = tid >> 6, lane = tid & 63;
  const int wg = w & 3, grp = w >> 2;
  const int l16 = lane & 15, quad = lane >> 4;
  const int g256 = tid & 255;

  __bf16* Ks  = KsAll + grp * (128 * LDPK);
  __bf16* Vts = VtsAll + grp * (64 * LDPV);

  const __bf16* Qb = QKV + (size_t)(b * NSEQ + qt * 256) * QKVD + h * 64;
  const __bf16* Kb = QKV + ((size_t)b * NSEQ + (size_t)grp * 2048) * QKVD + 512 + h * 64;
  const __bf16* Vp = Vtp + (size_t)bh * HD * NSEQ + grp * 2048;

  // Q fragments (one-time); both groups load the same rows
  bf16x8 aq[4][2];
#pragma unroll
  for (int mt = 0; mt < 4; ++mt)
#pragma unroll
    for (int c = 0; c < 2; ++c)
      aq[mt][c] = *(const bf16x8*)(Qb + (size_t)(wg * 64 + mt * 16 + l16) * QKVD +
                                   quad * 8 + c * 32);

  int krow[4], kc8[4], vd[4], vp8[4];
#pragma unroll
  for (int i = 0; i < 4; ++i) {
    int ch = g256 + i * 256;
    krow[i] = ch >> 3; kc8[i] = (ch & 7) << 3;
    vd[i] = ch >> 4;   vp8[i] = (ch & 15) << 3;
  }

  bf16x8 kreg[4], vreg[4];
#pragma unroll
  for (int i = 0; i < 4; ++i) {
    kreg[i] = *(const bf16x8*)(Kb + (size_t)krow[i] * QKVD + kc8[i]);
    vreg[i] = *(const bf16x8*)(Vp + (size_t)vd[i] * NSEQ + vp8[i]);
  }

  bf16x8 ones;
#pragma unroll
  for (int j = 0; j < 8; ++j) ones[j] = (__bf16)1.0f;

  f32x4 Oacc[4][5] = {};   // dt 0..3 = O, dt 4 = l (ones-column)

  for (int kt = 0; kt < 16; ++kt) {
    __syncthreads();
#pragma unroll
    for (int i = 0; i < 4; ++i) {
      *(bf16x8*)(Ks + krow[i] * LDPK + kc8[i]) = kreg[i];
      *(bf16x8*)(Vts + vd[i] * LDPV + vp8[i]) = vreg[i];
    }
    __syncthreads();

    if (kt + 1 < 16) {
      const __bf16* Kn = Kb + (size_t)(kt + 1) * 128 * QKVD;
      const __bf16* Vn = Vp + (size_t)(kt + 1) * 128;
#pragma unroll
      for (int i = 0; i < 4; ++i) {
        kreg[i] = *(const bf16x8*)(Kn + (size_t)krow[i] * QKVD + kc8[i]);
        vreg[i] = *(const bf16x8*)(Vn + (size_t)vd[i] * NSEQ + vp8[i]);
      }
    }

#pragma unroll
    for (int g = 0; g < 4; ++g) {
      bf16x8 kb[2][2];
#pragma unroll
      for (int e = 0; e < 2; ++e)
#pragma unroll
        for (int c = 0; c < 2; ++c)
          kb[e][c] = *(const bf16x8*)(Ks + ((2 * g + e) * 16 + l16) * LDPK +
                                      quad * 8 + c * 32);
      bf16x8 ap[4];
#pragma unroll
      for (int mt = 0; mt < 4; ++mt) {
        f32x4 a0 = {}, a1 = {};
        a0 = mfma32(kb[0][0], aq[mt][0], a0);
        a0 = mfma32(kb[0][1], aq[mt][1], a0);
        a1 = mfma32(kb[1][0], aq[mt][0], a1);
        a1 = mfma32(kb[1][1], aq[mt][1], a1);
        f32x4 e0, e1;
#pragma unroll
        for (int r = 0; r < 4; ++r) {
          e0[r] = __builtin_amdgcn_exp2f(a0[r]);
          e1[r] = __builtin_amdgcn_exp2f(a1[r]);
        }
        ap[mt] = __builtin_bit_cast(bf16x8,
            __builtin_shufflevector(pack_bf16(e0), pack_bf16(e1), 0, 1, 2, 3, 4, 5, 6, 7));
      }
#pragma unroll
      for (int dt = 0; dt < 4; ++dt) {
        bf16x8 bv = *(const bf16x8*)(Vts + (dt * 16 + l16) * LDPV + g * 32 + quad * 8);
#pragma unroll
        for (int mt = 0; mt < 4; ++mt)
          Oacc[mt][dt] = mfma32(ap[mt], bv, Oacc[mt][dt]);
      }
#pragma unroll
      for (int mt = 0; mt < 4; ++mt)
        Oacc[mt][4] = mfma32(ap[mt], ones, Oacc[mt][4]);   // l column
    }
  }

  // combine group partials via LDS (staging buffers are dead now)
  __syncthreads();
  if (grp == 1) {
#pragma unroll
    for (int mt = 0; mt < 4; ++mt)
#pragma unroll
      for (int dt = 0; dt < 5; ++dt)
        *(f32x4*)(Oex + (((wg * 4 + mt) * 5 + dt) << 8) + (lane << 2)) = Oacc[mt][dt];
  }
  __syncthreads();
  if (grp == 0) {
#pragma unroll
    for (int mt = 0; mt < 4; ++mt) {
#pragma unroll
      for (int dt = 0; dt < 5; ++dt)
        Oacc[mt][dt] += *(const f32x4*)(Oex + (((wg * 4 + mt) * 5 + dt) << 8) + (lane << 2));
#pragma unroll
      for (int r = 0; r < 4; ++r) {
        float inv = 1.0f / Oacc[mt][4][r];   // l for q-row quad*4+r
        int n = qt * 256 + wg * 64 + mt * 16 + quad * 4 + r;
        size_t base = ((size_t)b * NSEQ + n) * DIM + (size_t)h * HD;
#pragma unroll
        for (int dt = 0; dt < 4; ++dt)
          Og[base + dt * 16 + l16] = (__bf16)(Oacc[mt][dt][r] * inv);
      }
    }
  }
}

extern "C" void kernel_launch(void* const* d_in, const int* in_sizes, int n_in,
                              void* d_out, int out_size, void* d_ws, size_t ws_size,
                              hipStream_t stream) {
  const float* x      = (const float*)d_in[0];   // [2,4096,512]
  const float* qkv_w  = (const float*)d_in[1];   // [1536,512]
  const float* qkv_b  = (const float*)d_in[2];   // [1536]
  const float* proj_w = (const float*)d_in[3];   // [512,512]
  const float* proj_b = (const float*)d_in[4];   // [512]
  float* out = (float*)d_out;                    // [2,4096,512] fp32

  char* ws = (char*)d_ws;
  __bf16* Vtw   = (__bf16*)(ws);                 // 8 MB [B,H,HD,N] permuted
  __bf16* qkvC  = (__bf16*)(ws + 8388608);       // 24 MB [8192][1536] (V third unused)
  __bf16* wqkv  = (__bf16*)(ws + 33554432);      // 1.5 MB
  __bf16* wproj = (__bf16*)(ws + 35127296);      // 0.5 MB
  __bf16* Ob    = (__bf16*)(ws + 35651584);      // 8 MB context [m][512]
  // xb aliases Ob: xb is dead after gemm_qkv; Ob first written by attn_fused
  // (stream-ordered after gemm_qkv) -> no overlap in lifetime.
  __bf16* xb    = (__bf16*)(ws + 35651584);      // 8 MB x in bf16 [8192][512]
  // total 44,040,192 B

  cvt_all<<<5120, 256, 0, stream>>>(x, qkv_w, proj_w, xb, wqkv, wproj);
  gemm_qkv<<<dim3(64, 12), 256, 0, stream>>>(xb, wqkv, qkv_b, qkvC, Vtw);
  attn_fused<<<dim3(16, 16), 512, 0, stream>>>(qkvC, Vtw, Ob);
  gemm_proj<<<dim3(64, 8), 256, 0, stream>>>(Ob, wproj, proj_b, out);
}